// Round 3
// baseline (82.589 us; speedup 1.0000x reference)
//
#include <hip/hip_runtime.h>

// x[16,64,96,96] f32, dict[100,64,3,3] f32, coeff[256,3,3,3] f32, idx[256,3,3,3] i32
// out[16,256,96,96] f32
#define NB   16
#define CIN  64
#define HH   96
#define WW   96
#define DD   100
#define OO   256
#define NWG  (NB * HH)   // 1536

typedef __attribute__((ext_vector_type(8))) short  bf16x8;
typedef __attribute__((ext_vector_type(4))) float  f32x4;

static __device__ __forceinline__ unsigned short f32_to_bf16(float f) {
    unsigned int u = __float_as_uint(f);
    u += 0x7FFFu + ((u >> 16) & 1u);   // RNE
    return (unsigned short)(u >> 16);
}

// swizzle: granule-XOR that spreads both the read pattern (16 consecutive wp)
// and the staging write pattern (wp stride 4) across 8 granule classes
#define FSWZ(wp) ((((wp) ^ ((wp) >> 3)) & 7) << 4)

// ---- prep: W_eff = (scatter(coeff,idx) @ dict) in MFMA B-fragment lane order.
// frag(kpos, otile, ks) is 1KB: halfword index = (kpos*32 + otile*2 + ks)*512 + lane*8 + e
__global__ __launch_bounds__(256) void weff_prep(
    const float* __restrict__ dict, const float* __restrict__ coeff,
    const int* __restrict__ idx, unsigned short* __restrict__ weff2)
{
    __shared__ float wrow[DD];
    const int o = blockIdx.x, tid = threadIdx.x;
    if (tid < DD) wrow[tid] = 0.f;
    __syncthreads();
    if (tid == 0) {                              // deterministic serial scatter
        for (int s = 0; s < 27; ++s) wrow[idx[o * 27 + s]] += coeff[o * 27 + s];
    }
    __syncthreads();
    for (int j = tid; j < 576; j += 256) {       // j = kpos*64 + c
        int kpos = j >> 6, c = j & 63;
        float s = 0.f;
        for (int d = 0; d < DD; ++d)
            s += wrow[d] * dict[d * 576 + c * 9 + kpos];
        int otile = o >> 4, ks = c >> 5;
        int lane8 = (o & 15) | (((c >> 3) & 3) << 4);
        weff2[((size_t)(kpos * 32 + otile * 2 + ks)) * 512 + lane8 * 8 + (c & 7)]
            = f32_to_bf16(s);
    }
}

// ---- conv: block = (b,h) output row; 8 waves 2(w-half) x 4(o-quarter).
// Stages x (f32 NCHW) -> bf16 swizzled LDS directly (no x2 intermediate).
// 18 unrolled (kpos,ks) half-steps, 2-bank B-fragment prefetch, no k-loop barriers.
__global__ __launch_bounds__(512, 4) void conv_kernel(
    const float* __restrict__ x,               // [16][64][96][96] f32
    const unsigned short* __restrict__ weff2,  // fragment-ordered, 288KB (L2-resident)
    float* __restrict__ out)                   // [16][256][96][96] f32
{
    __shared__ unsigned short xs[3 * 98 * 64]; // 3 rows, wp in [0,98), swizzled. 37632 B

    const int wg  = blockIdx.x;
    const int swz = (wg & 7) * (NWG / 8) + (wg >> 3);   // XCD-bijective (1536%8==0)
    const int b = swz / HH, h = swz % HH;
    const int tid = threadIdx.x;
    const int lane = tid & 63, wid = tid >> 6;
    const int wm = wid >> 2, wn = wid & 3;     // wm: w-half, wn: o-quarter

    char* xsb = reinterpret_cast<char*>(xs);

    // ---- issue B-fragment loads for steps 0,1 before staging (fly under it) ----
    const unsigned short* wp_base = weff2 + (size_t)(wn * 8) * 512 + lane * 8;
    bf16x8 bA[4], bB[4];
#pragma unroll
    for (int n = 0; n < 4; ++n)
        bA[n] = *reinterpret_cast<const bf16x8*>(wp_base + (n * 2 + 0) * 512);
#pragma unroll
    for (int n = 0; n < 4; ++n)
        bB[n] = *reinterpret_cast<const bf16x8*>(wp_base + (n * 2 + 1) * 512);

    // ---- stage 3 x rows (h-1..h+1): f32 coalesced read -> bf16 scatter write ----
    const float* xb = x + (size_t)b * CIN * HH * WW;
#pragma unroll
    for (int it = 0; it < 9; ++it) {
        int k = tid + it * 512;                // 3*64*24 = 4608 float4 chunks
        int r = k / 1536, rem = k % 1536;
        int c = rem / 24, w4 = rem % 24;
        int hp = h - 1 + r;
        float4 v = {0.f, 0.f, 0.f, 0.f};
        if (hp >= 0 && hp < HH)
            v = *reinterpret_cast<const float4*>(xb + ((size_t)c * HH + hp) * WW + w4 * 4);
        int rb = r * 12544;
#pragma unroll
        for (int j = 0; j < 4; ++j) {
            int wpos = w4 * 4 + j + 1;
            float f = (j == 0) ? v.x : (j == 1) ? v.y : (j == 2) ? v.z : v.w;
            int lb = rb + ((wpos * 128 + c * 2) ^ FSWZ(wpos));
            *reinterpret_cast<unsigned short*>(xsb + lb) = f32_to_bf16(f);
        }
    }
    if (tid < 48) {                            // zero pad wp=0 and wp=97
        int r = tid / 16, side = (tid & 15) >> 3, ci = tid & 7;
        int wpos = side ? 97 : 0;
        int lb = r * 12544 + ((wpos * 128 + ci * 16) ^ FSWZ(wpos));
        bf16x8 z = {0,0,0,0,0,0,0,0};
        *reinterpret_cast<bf16x8*>(xsb + lb) = z;
    }

    f32x4 acc[3][4];
#pragma unroll
    for (int m = 0; m < 3; ++m)
#pragma unroll
        for (int n = 0; n < 4; ++n)
            acc[m][n] = (f32x4){0.f, 0.f, 0.f, 0.f};

    __syncthreads();                           // xs staged (only barrier)

    const int wbase = wm * 48 + (lane & 15);

    // ---- 18 half-steps: step s = (kpos = s>>1, ks = s&1). Bank A = even s, B = odd.
#pragma unroll
    for (int s = 0; s < 18; ++s) {
        const int kpos = s >> 1, ks = s & 1;
        const int r = kpos / 3, dw = kpos % 3;
        const int cb2 = (ks * 32 + (lane >> 4) * 8) * 2;   // byte offset of c
        const int rb = r * 12544;
#pragma unroll
        for (int m = 0; m < 3; ++m) {
            int wpos = wbase + m * 16 + dw;
            int lb = rb + ((wpos * 128 + cb2) ^ FSWZ(wpos));
            bf16x8 a = *reinterpret_cast<const bf16x8*>(xsb + lb);
#pragma unroll
            for (int n = 0; n < 4; ++n)
                acc[m][n] = __builtin_amdgcn_mfma_f32_16x16x32_bf16(
                    a, (s & 1) ? bB[n] : bA[n], acc[m][n], 0, 0, 0);
        }
        // reload this bank with step s+2's fragments (prefetch distance 2)
        if (s < 16) {
            const int s2 = s + 2;
            const int off = ((s2 >> 1) * 32 + (s2 & 1)) * 512;
#pragma unroll
            for (int n = 0; n < 4; ++n) {
                bf16x8 v = *reinterpret_cast<const bf16x8*>(wp_base + off + n * 2 * 512);
                if ((s & 1) == 0) bA[n] = v; else bB[n] = v;
            }
        }
    }

    // ---- epilogue: lane holds 4 consecutive w (row=(lane>>4)*4), o = col=lane&15
#pragma unroll
    for (int m = 0; m < 3; ++m) {
#pragma unroll
        for (int n = 0; n < 4; ++n) {
            int o = wn * 64 + n * 16 + (lane & 15);
            int w = wm * 48 + m * 16 + (lane >> 4) * 4;
            *reinterpret_cast<float4*>(
                out + (((size_t)(b * OO + o) * HH + h) * WW + w))
                = *reinterpret_cast<float4*>(&acc[m][n]);
        }
    }
}

extern "C" void kernel_launch(void* const* d_in, const int* in_sizes, int n_in,
                              void* d_out, int out_size, void* d_ws, size_t ws_size,
                              hipStream_t stream) {
    const float* x     = (const float*)d_in[0];
    const float* dict  = (const float*)d_in[1];
    const float* coeff = (const float*)d_in[2];
    const int*   idx   = (const int*)d_in[3];
    float* out = (float*)d_out;

    unsigned short* weff2 = (unsigned short*)d_ws;   // 294912 B

    weff_prep<<<OO, 256, 0, stream>>>(dict, coeff, idx, weff2);
    conv_kernel<<<NWG, 512, 0, stream>>>(x, weff2, out);
}